// Round 7
// baseline (211.602 us; speedup 1.0000x reference)
//
#include <hip/hip_runtime.h>

#define N_NODES 100000
#define N_EDGES 1600000
#define NB 782    // ceil(N_NODES/128) buckets of 128 dst-nodes
#define CAP 3072  // strip capacity per bucket (mean 2046, sigma 45 -> 22-sigma safe)
#define P1B 391   // pass1 blocks (4096 edges each)
#define CVB 625   // convert blocks
#define YP 72     // padded LDS row (bf16 elems) for weights / y tile
#define AP 72     // padded LDS agg row (bf16 elems)

typedef __attribute__((ext_vector_type(8))) short bhalf8;
typedef __attribute__((ext_vector_type(4))) float f32x4;

__device__ __forceinline__ unsigned short bf16r(float f) {
    unsigned u = __float_as_uint(f);
    unsigned r = (u >> 16) & 1;
    return (unsigned short)((u + 0x7fffu + r) >> 16);
}
__device__ __forceinline__ unsigned pk2(float a, float b) {
    return (unsigned)bf16r(a) | ((unsigned)bf16r(b) << 16);
}
__device__ __forceinline__ float bl(unsigned u) { return __uint_as_float(u << 16); }
__device__ __forceinline__ float bh(unsigned u) { return __uint_as_float(u & 0xffff0000u); }

// ---------------- prep: pass1 (blocks 0..P1B-1) || convert (blocks P1B..) ------
// pass1: scatter packed (src<<7|dstlocal) into bucket strips (relative cursors,
// gcur pre-zeroed by hipMemsetAsync). convert: features fp32 -> bf16.
__global__ __launch_bounds__(256) void prep(const float4* __restrict__ X4,
                                            uint2* __restrict__ Xb,
                                            const int* __restrict__ src,
                                            const int* __restrict__ dst,
                                            int* __restrict__ gcur,
                                            unsigned* __restrict__ ebuf) {
    __shared__ int h[NB];
    __shared__ int cur[NB];
    int t = threadIdx.x;
    if (blockIdx.x < P1B) {
        for (int b = t; b < NB; b += 256) h[b] = 0;
        __syncthreads();
        int e0 = blockIdx.x * 4096 + t;
        unsigned pk[16]; int bk[16];
#pragma unroll
        for (int i = 0; i < 16; i++) {
            int e = e0 + i * 256;
            if (e < N_EDGES) {
                int s = src[e], d = dst[e];
                bk[i] = d >> 7;
                pk[i] = ((unsigned)s << 7) | (unsigned)(d & 127);
                atomicAdd(&h[bk[i]], 1);
            } else bk[i] = -1;
        }
        __syncthreads();
        for (int b = t; b < NB; b += 256)
            cur[b] = h[b] ? (b * CAP + atomicAdd(&gcur[b], h[b])) : 0;
        __syncthreads();
#pragma unroll
        for (int i = 0; i < 16; i++)
            if (bk[i] >= 0) {
                int r = atomicAdd(&cur[bk[i]], 1);
                ebuf[r] = pk[i];
            }
    } else {
        for (int i = (blockIdx.x - P1B) * 256 + t; i < N_NODES * 16; i += CVB * 256) {
            float4 v = X4[i];
            uint2 o; o.x = pk2(v.x, v.y); o.y = pk2(v.z, v.w);
            Xb[i] = o;
        }
    }
}

// ---------------- bucket1: pass2 + gather1 + gemm12 fused, 1 block per bucket --
// Phases: hist -> scan -> off/deg/csr -> LDS sort (stg) -> gather X rows into
// LDS agg tile (bf16) -> MFMA: Zb = relu(agg@W1+b1)@W2 written straight out.
__global__ __launch_bounds__(1024) void bucket1(
    const unsigned* __restrict__ ebuf, const int* __restrict__ gcur,
    const uint4* __restrict__ Xb4,
    const float* __restrict__ W1, const float* __restrict__ b1,
    const float* __restrict__ W2,
    int* __restrict__ off, int* __restrict__ deg, int* __restrict__ csr,
    unsigned short* __restrict__ Zb) {
    __shared__ int hh[128], nodeoff[129], scv[128];
    __shared__ unsigned short sW1t[64 * YP];   // W1^T [h][k]
    __shared__ unsigned short sW2t[32 * YP];   // W2^T [oc][h]
    __shared__ unsigned short agg[128 * AP];   // agg tile [node_local][ch]
    __shared__ int stg[CAP];                   // sorted src list; reused as sy
    unsigned short* sy = (unsigned short*)stg; // 4 waves x 16 x YP = 9216 B <= 12288 B

    int b = blockIdx.x, t = threadIdx.x;
    int base = b * CAP, cnt = gcur[b];
    if (t < 128) hh[t] = 0;
    for (int i = t; i < 64 * 64; i += 1024) {
        int k = i >> 6, hc = i & 63;
        sW1t[hc * YP + k] = bf16r(W1[k * 64 + hc]);
    }
    for (int i = t; i < 64 * 32; i += 1024) {
        int k = i >> 5, oc = i & 31;
        sW2t[oc * YP + k] = bf16r(W2[k * 32 + oc]);
    }
    __syncthreads();
    for (int i = t; i < cnt; i += 1024) atomicAdd(&hh[ebuf[base + i] & 127], 1);
    __syncthreads();
    if (t == 0) {
        int a = 0;
        for (int k = 0; k < 128; k++) { nodeoff[k] = a; a += hh[k]; }
        nodeoff[128] = a;
    }
    __syncthreads();
    if (t < 128) {
        int n = b * 128 + t;
        if (n < N_NODES) { off[n] = base + nodeoff[t]; deg[n] = hh[t]; }
        scv[t] = nodeoff[t];
    }
    __syncthreads();
    for (int i = t; i < cnt; i += 1024) {
        unsigned v = ebuf[base + i];
        int r = atomicAdd(&scv[v & 127], 1);
        stg[r] = (int)(v >> 7);
    }
    __syncthreads();
    // coalesced CSR write (for gather2) — stg is read-only from here to next sync
    for (int i = t; i < cnt; i += 1024) csr[base + i] = stg[i];

    // ---- gather phase: 16 waves x 8 consecutive nodes each ----
    int lane = t & 63, wid = t >> 6;
    int il = lane & 7, g = lane >> 3;
#pragma unroll 1
    for (int nl = wid * 8; nl < wid * 8 + 8; nl++) {
        int s0 = nodeoff[nl], d = hh[nl];
        float a0 = 0.f, a1 = 0.f, a2 = 0.f, a3 = 0.f;
        float a4 = 0.f, a5 = 0.f, a6 = 0.f, a7 = 0.f;
        int j = g;
        for (; j + 8 < d; j += 16) {
            int sa = stg[s0 + j], sb = stg[s0 + j + 8];
            uint4 va = Xb4[sa * 8 + il], vb = Xb4[sb * 8 + il];
            a0 += bl(va.x) + bl(vb.x); a1 += bh(va.x) + bh(vb.x);
            a2 += bl(va.y) + bl(vb.y); a3 += bh(va.y) + bh(vb.y);
            a4 += bl(va.z) + bl(vb.z); a5 += bh(va.z) + bh(vb.z);
            a6 += bl(va.w) + bl(vb.w); a7 += bh(va.w) + bh(vb.w);
        }
        if (j < d) {
            int sa = stg[s0 + j];
            uint4 va = Xb4[sa * 8 + il];
            a0 += bl(va.x); a1 += bh(va.x); a2 += bl(va.y); a3 += bh(va.y);
            a4 += bl(va.z); a5 += bh(va.z); a6 += bl(va.w); a7 += bh(va.w);
        }
#pragma unroll
        for (int m = 8; m < 64; m <<= 1) {
            a0 += __shfl_xor(a0, m); a1 += __shfl_xor(a1, m);
            a2 += __shfl_xor(a2, m); a3 += __shfl_xor(a3, m);
            a4 += __shfl_xor(a4, m); a5 += __shfl_xor(a5, m);
            a6 += __shfl_xor(a6, m); a7 += __shfl_xor(a7, m);
        }
        if (g == 0) {
            uint4 o;
            o.x = pk2(a0, a1); o.y = pk2(a2, a3);
            o.z = pk2(a4, a5); o.w = pk2(a6, a7);
            *(uint4*)&agg[nl * AP + il * 8] = o;  // nl*144 + il*16 bytes, 16B aligned
        }
    }
    __syncthreads();

    // ---- MFMA phase: waves 0..3, 2 node-tiles (16 nodes) each ----
    if (wid < 4) {
        int m = lane & 15, quad = lane >> 4;
        bhalf8 A1[4][2], A2[2][2];
#pragma unroll
        for (int tile = 0; tile < 4; tile++)
#pragma unroll
            for (int c = 0; c < 2; c++)
                A1[tile][c] = *(const bhalf8*)&sW1t[(tile * 16 + m) * YP + c * 32 + quad * 8];
#pragma unroll
        for (int tile = 0; tile < 2; tile++)
#pragma unroll
            for (int c = 0; c < 2; c++)
                A2[tile][c] = *(const bhalf8*)&sW2t[(tile * 16 + m) * YP + c * 32 + quad * 8];
        f32x4 bias1[4];
#pragma unroll
        for (int tile = 0; tile < 4; tile++)
#pragma unroll
            for (int r = 0; r < 4; r++) bias1[tile][r] = b1[tile * 16 + quad * 4 + r];
        unsigned short* yt = sy + wid * 16 * YP;
#pragma unroll
        for (int tt = 0; tt < 2; tt++) {
            int nl = (wid * 2 + tt) * 16 + m;
            int node = b * 128 + nl;
            bhalf8 Bc0 = *(const bhalf8*)&agg[nl * AP + quad * 8];
            bhalf8 Bc1 = *(const bhalf8*)&agg[nl * AP + 32 + quad * 8];
#pragma unroll
            for (int tile = 0; tile < 4; tile++) {
                f32x4 a = bias1[tile];
                a = __builtin_amdgcn_mfma_f32_16x16x32_bf16(A1[tile][0], Bc0, a, 0, 0, 0);
                a = __builtin_amdgcn_mfma_f32_16x16x32_bf16(A1[tile][1], Bc1, a, 0, 0, 0);
                float y0 = a[0] > 0.f ? a[0] : 0.f, y1 = a[1] > 0.f ? a[1] : 0.f;
                float y2 = a[2] > 0.f ? a[2] : 0.f, y3 = a[3] > 0.f ? a[3] : 0.f;
                uint2 o; o.x = pk2(y0, y1); o.y = pk2(y2, y3);
                *(uint2*)&yt[m * YP + tile * 16 + quad * 4] = o;
            }
            bhalf8 Y0 = *(const bhalf8*)&yt[m * YP + quad * 8];
            bhalf8 Y1 = *(const bhalf8*)&yt[m * YP + 32 + quad * 8];
#pragma unroll
            for (int tile = 0; tile < 2; tile++) {
                f32x4 z = {0.f, 0.f, 0.f, 0.f};
                z = __builtin_amdgcn_mfma_f32_16x16x32_bf16(A2[tile][0], Y0, z, 0, 0, 0);
                z = __builtin_amdgcn_mfma_f32_16x16x32_bf16(A2[tile][1], Y1, z, 0, 0, 0);
                if (node < N_NODES) {
                    uint2 o; o.x = pk2(z[0], z[1]); o.y = pk2(z[2], z[3]);
                    *(uint2*)&Zb[(size_t)node * 32 + tile * 16 + quad * 4] = o;
                }
            }
        }
    }
}

// ---------------- gather 2: out[n] = sum Zb[src] + b2 (fp32 out) ----------------
__global__ __launch_bounds__(256) void gather2(
    const uint2* __restrict__ Zb2, const int* __restrict__ off,
    const int* __restrict__ deg, const int* __restrict__ csr,
    const float* __restrict__ b2, float4* __restrict__ out4) {
    int t = threadIdx.x, lane = t & 63, wid = t >> 6;
    int il = lane & 7, g = lane >> 3;
    float4 bb = ((const float4*)b2)[il];
    int w0 = blockIdx.x * 4 + wid, stride = gridDim.x * 4;
    for (int n = w0; n < N_NODES; n += stride) {
        int s0 = off[n], d = deg[n];
        float a0 = 0.f, a1 = 0.f, a2 = 0.f, a3 = 0.f;
        int j = g;
        for (; j + 8 < d; j += 16) {
            int sa = csr[s0 + j], sb = csr[s0 + j + 8];
            uint2 va = Zb2[sa * 8 + il], vb = Zb2[sb * 8 + il];
            a0 += bl(va.x) + bl(vb.x); a1 += bh(va.x) + bh(vb.x);
            a2 += bl(va.y) + bl(vb.y); a3 += bh(va.y) + bh(vb.y);
        }
        if (j < d) {
            int sa = csr[s0 + j];
            uint2 va = Zb2[sa * 8 + il];
            a0 += bl(va.x); a1 += bh(va.x); a2 += bl(va.y); a3 += bh(va.y);
        }
#pragma unroll
        for (int m = 8; m < 64; m <<= 1) {
            a0 += __shfl_xor(a0, m); a1 += __shfl_xor(a1, m);
            a2 += __shfl_xor(a2, m); a3 += __shfl_xor(a3, m);
        }
        if (g == 0) {
            float4 o;
            o.x = a0 + bb.x; o.y = a1 + bb.y; o.z = a2 + bb.z; o.w = a3 + bb.w;
            out4[n * 8 + il] = o;
        }
    }
}

extern "C" void kernel_launch(void* const* d_in, const int* in_sizes, int n_in,
                              void* d_out, int out_size, void* d_ws, size_t ws_size,
                              hipStream_t stream) {
    const float* features = (const float*)d_in[0];
    const int*   src      = (const int*)d_in[1];
    const int*   dst      = (const int*)d_in[2];
    const float* W1       = (const float*)d_in[3];
    const float* b1       = (const float*)d_in[4];
    const float* W2       = (const float*)d_in[5];
    const float* b2       = (const float*)d_in[6];

    char* p = (char*)d_ws;
    int* gcur = (int*)p;       p += 1024 * 4;
    int* off  = (int*)p;       p += ((size_t)N_NODES * 4 + 255) / 256 * 256;
    int* deg  = (int*)p;       p += ((size_t)N_NODES * 4 + 255) / 256 * 256;
    unsigned* ebuf = (unsigned*)p; p += (size_t)NB * CAP * 4;
    int* csr  = (int*)p;       p += (size_t)NB * CAP * 4;
    uint2* Xb = (uint2*)p;     p += (size_t)N_NODES * 64 * 2;
    unsigned short* Zb = (unsigned short*)p; p += (size_t)N_NODES * 32 * 2;

    hipMemsetAsync(gcur, 0, NB * sizeof(int), stream);
    prep<<<P1B + CVB, 256, 0, stream>>>((const float4*)features, Xb, src, dst, gcur, ebuf);
    bucket1<<<NB, 1024, 0, stream>>>(ebuf, gcur, (const uint4*)Xb, W1, b1, W2,
                                     off, deg, csr, Zb);
    gather2<<<2048, 256, 0, stream>>>((const uint2*)Zb, off, deg, csr, b2, (float4*)d_out);
}